// Round 1
// 213.121 us; speedup vs baseline: 1.0537x; 1.0537x over previous
//
#include <hip/hip_runtime.h>
#include <hip/hip_bf16.h>
#include <math.h>

// GATv2 encoder, bucketed ushort-ELL (width 64, padded rows):
//   prep(fold+cat2+zero) -> part(LDS hist) -> ellb(LDS slot assign + pad + flush)
//   -> gemm1(16-deep prefetch) -> node_conv1(ring4 + FUSED gemm2 via LDS tile)
//   -> node_conv2 -> out
// Lessons: grid.sync ~60us (R8); per-block __threadfence serializes (R10);
// kernel merging never overlaps, random global atomics saturate ~13 G/s
// (R13/R16); ELL pad kills prefetch clamps (R18); producer-block GEMM fusion
// removes the H1 round-trip (R19).
// This round: shfl_xor reduce -> DPP v_add (kills 3.1M ds_swizzle + 1.2M
// bank-conflict cycles + lgkmcnt chains); unconditional 4-wide PROC with
// pad-duplicate subtraction (pads are self rows, weight identical); ushort4
// neighbor-index loads.

#define NEG_SLOPE 0.2f
#define LOG2E 1.4426950408889634f
#define NREP 16
#define ELLW 64
#define CH 2048
#define CAPB 8192

typedef __attribute__((ext_vector_type(8))) short bf16x8;
typedef __attribute__((ext_vector_type(4))) float f32x4;

__device__ __forceinline__ float leaky(float t) { return fmaxf(t, NEG_SLOPE * t); }
__device__ __forceinline__ float bf2f(unsigned short u) {
    return __uint_as_float((unsigned)u << 16);
}
__device__ __forceinline__ short f2bf(float f) {           // RNE
    __hip_bfloat16 h = __float2bfloat16(f);
    return *reinterpret_cast<short*>(&h);
}
__device__ __forceinline__ short f2bf_fast(float f) {      // round-half-up
    return (short)((__float_as_uint(f) + 0x8000u) >> 16);
}

// DPP cross-lane add: v += lane-permuted(v). CTRL: 0xB1 quad xor1,
// 0x4E quad xor2, 0x124 row_ror:4, 0x128 row_ror:8, 0x141 row_half_mirror.
template <int CTRL>
__device__ __forceinline__ float dppadd(float v) {
    int t = __builtin_amdgcn_update_dpp(0, __float_as_int(v), CTRL, 0xF, 0xF, true);
    return v + __int_as_float(t);
}

// ============ prep: fold1 (b<128) + cat2 (128<=b<160) + zero (b>=160) ============
__global__ __launch_bounds__(256) void prep_kernel(const float* __restrict__ Win,
                                                   const float* __restrict__ b_in,
                                                   const float* __restrict__ Wl1,
                                                   const float* __restrict__ bl1,
                                                   const float* __restrict__ Wr1,
                                                   const float* __restrict__ br1,
                                                   const float* __restrict__ Wl2,
                                                   const float* __restrict__ bl2,
                                                   const float* __restrict__ Wr2,
                                                   const float* __restrict__ br2,
                                                   unsigned short* __restrict__ Wcat1,
                                                   float* __restrict__ bcat1,
                                                   unsigned short* __restrict__ Wcat2,
                                                   float* __restrict__ bcat2,
                                                   int* __restrict__ bucketCnt,
                                                   float* __restrict__ pooledR, int N) {
    int b = blockIdx.x, t = threadIdx.x;
    if (b < 128) {
        int half = t >> 7;
        int k = t & 127;
        int o = b * 2 + half;
        const float* Wx = (o < 128) ? Wl1 : Wr1;
        const float* bx = (o < 128) ? bl1 : br1;
        int oo = o & 127;
        float acc = 0.f;
#pragma unroll 16
        for (int j = 0; j < 128; ++j)
            acc = fmaf(Wx[oo * 128 + j], Win[j * 128 + k], acc);
        Wcat1[o * 128 + k] = (unsigned short)f2bf(acc);

        __shared__ float red[256];
        red[t] = Wx[oo * 128 + k] * b_in[k];
        __syncthreads();
        for (int off = 64; off > 0; off >>= 1) {
            if (k < off) red[t] += red[t + off];
            __syncthreads();
        }
        if (k == 0) bcat1[o] = red[half * 128] + bx[oo];
    } else if (b < 160) {
        int i = (b - 128) * 256 + t;
        int m = i >> 7, kk = i & 127;
        float v = (m < 32) ? Wl2[m * 128 + kk] : Wr2[(m - 32) * 128 + kk];
        Wcat2[i] = (unsigned short)f2bf(v);
        if (b == 128 && t < 64) bcat2[t] = (t < 32) ? bl2[t] : br2[t - 32];
    } else if (b == 160) {
        if (t < 256) bucketCnt[t] = 0;
    } else {
        int i = (b - 161) * 256 + t;
        if (i < NREP * 32) pooledR[i] = 0.f;
    }
}

// ======== partition: chunk -> LDS hist -> reserve ranges -> packed write ========
__global__ __launch_bounds__(256) void part_kernel(const int* __restrict__ ei,
                                                   int* __restrict__ bucketCnt,
                                                   unsigned int* __restrict__ region,
                                                   int E) {
    __shared__ int hist[256];
    __shared__ int base[256];
    __shared__ int off[256];
    int b = blockIdx.x, t = threadIdx.x;
    int e0 = b * CH;
    int e1 = e0 + CH; if (e1 > E) e1 = E;

    hist[t] = 0;
    __syncthreads();
    for (int e = e0 + t; e < e1; e += 256) {
        int d = ei[E + e];
        atomicAdd(&hist[d >> 8], 1);
    }
    __syncthreads();
    int h = hist[t];
    base[t] = (h > 0) ? atomicAdd(&bucketCnt[t], h) : 0;
    off[t] = 0;
    __syncthreads();
    for (int e = e0 + t; e < e1; e += 256) {
        int s = ei[e];
        int d = ei[E + e];
        int bk = d >> 8;
        int p = base[bk] + atomicAdd(&off[bk], 1);
        if (p < CAPB)
            region[(size_t)bk * CAPB + p] = (unsigned)s | ((unsigned)(d & 255) << 16);
    }
}

// ======== ELL build: LDS atomics + 8-slot pad + coalesced flush ========
__global__ __launch_bounds__(256) void ellb_kernel(const unsigned int* __restrict__ region,
                                                   const int* __restrict__ bucketCnt,
                                                   unsigned short* __restrict__ ell,
                                                   int* __restrict__ deg, int N) {
    __shared__ unsigned short tile[256 * ELLW];  // 32 KB
    __shared__ int cur[256];
    int nb = blockIdx.x, t = threadIdx.x;
    cur[t] = 0;
    __syncthreads();
    int cnt = bucketCnt[nb];
    if (cnt > CAPB) cnt = CAPB;
    for (int i = t; i < cnt; i += 256) {
        unsigned p = region[(size_t)nb * CAPB + i];
        int doff = p >> 16;
        int s = p & 0xFFFF;
        int r = atomicAdd(&cur[doff], 1);
        if (r < ELLW) tile[doff * ELLW + r] = (unsigned short)s;
    }
    __syncthreads();
    int node = nb * 256 + t;
    int dgl = cur[t];
    if (dgl > ELLW) dgl = ELLW;
    if (node < N) {
        deg[node] = dgl;
        int pe = dgl + 8; if (pe > ELLW) pe = ELLW;
        for (int r = dgl; r < pe; ++r) tile[t * ELLW + r] = (unsigned short)node;
    }
    __syncthreads();
    const uint4* tl = (const uint4*)tile;
    uint4* gl = (uint4*)(ell + (size_t)nb * 256 * ELLW);
#pragma unroll
    for (int k = 0; k < 8; ++k) {
        int idx = t + k * 256;
        int row = idx >> 3;
        if (nb * 256 + row < N) gl[idx] = tl[idx];
    }
}

// ---------------- gemm1: f32 A, 16-deep prefetch, 32 rows x 256 ch ----------------
__global__ __launch_bounds__(256) void gemm1_kernel(const float* __restrict__ x,
                                                    const unsigned short* __restrict__ W,
                                                    const float* __restrict__ bias,
                                                    unsigned short* __restrict__ XL,
                                                    unsigned short* __restrict__ XR, int N) {
    const int w = threadIdx.x >> 6;
    const int lane = threadIdx.x & 63;
    const int ln = lane & 15;
    const int quad = lane >> 4;
    const int nb = blockIdx.x * 32;
    const int c0 = w * 64;

    int rows[2];
#pragma unroll
    for (int rt = 0; rt < 2; ++rt) {
        int n = nb + rt * 16 + ln;
        rows[rt] = n < N ? n : N - 1;
    }

    float4 araw[2][4][2];
#pragma unroll
    for (int rt = 0; rt < 2; ++rt)
#pragma unroll
        for (int kc = 0; kc < 4; ++kc) {
            const float* p = x + (size_t)rows[rt] * 128 + kc * 32 + quad * 8;
            araw[rt][kc][0] = *(const float4*)p;
            araw[rt][kc][1] = *(const float4*)(p + 4);
        }
    bf16x8 a[2][4];
#pragma unroll
    for (int rt = 0; rt < 2; ++rt)
#pragma unroll
        for (int kc = 0; kc < 4; ++kc) {
            float4 u = araw[rt][kc][0], v = araw[rt][kc][1];
            a[rt][kc][0] = f2bf_fast(u.x); a[rt][kc][1] = f2bf_fast(u.y);
            a[rt][kc][2] = f2bf_fast(u.z); a[rt][kc][3] = f2bf_fast(u.w);
            a[rt][kc][4] = f2bf_fast(v.x); a[rt][kc][5] = f2bf_fast(v.y);
            a[rt][kc][6] = f2bf_fast(v.z); a[rt][kc][7] = f2bf_fast(v.w);
        }

    f32x4 acc[2][4];
#pragma unroll
    for (int rt = 0; rt < 2; ++rt)
#pragma unroll
        for (int ct = 0; ct < 4; ++ct) acc[rt][ct] = (f32x4){0.f, 0.f, 0.f, 0.f};

#pragma unroll
    for (int kc = 0; kc < 4; ++kc) {
        const int k0 = kc * 32 + quad * 8;
        bf16x8 wv[4];
#pragma unroll
        for (int ct = 0; ct < 4; ++ct)
            wv[ct] = *(const bf16x8*)(W + (size_t)(c0 + ct * 16 + ln) * 128 + k0);
#pragma unroll
        for (int rt = 0; rt < 2; ++rt)
#pragma unroll
            for (int ct = 0; ct < 4; ++ct)
                acc[rt][ct] = __builtin_amdgcn_mfma_f32_16x16x32_bf16(wv[ct], a[rt][kc], acc[rt][ct], 0, 0, 0);
    }

#pragma unroll
    for (int rt = 0; rt < 2; ++rt) {
        int n = nb + rt * 16 + ln;
        if (n >= N) continue;
#pragma unroll
        for (int ct = 0; ct < 4; ++ct) {
            int cb = c0 + ct * 16 + quad * 4;
            float4 bv = *(const float4*)&bias[cb];
            ushort4 o;
            o.x = (unsigned short)f2bf(acc[rt][ct][0] + bv.x);
            o.y = (unsigned short)f2bf(acc[rt][ct][1] + bv.y);
            o.z = (unsigned short)f2bf(acc[rt][ct][2] + bv.z);
            o.w = (unsigned short)f2bf(acc[rt][ct][3] + bv.w);
            if (cb < 128) *(ushort4*)&XL[(size_t)n * 128 + cb] = o;
            else          *(ushort4*)&XR[(size_t)n * 128 + cb - 128] = o;
        }
    }
}

// ======= conv1 + fused gemm2: 8 nodes/block; ring4 gather then LDS-tile MFMA =======
__global__ __launch_bounds__(256) void node_conv1(const unsigned short* __restrict__ XL,
                                                  const unsigned short* __restrict__ XR,
                                                  const int* __restrict__ deg,
                                                  const unsigned short* __restrict__ ell,
                                                  const float* __restrict__ att,
                                                  const float* __restrict__ bias,
                                                  const unsigned short* __restrict__ Wcat2,
                                                  const float* __restrict__ bcat2,
                                                  unsigned short* __restrict__ XL2,
                                                  unsigned short* __restrict__ XR2, int N) {
    __shared__ unsigned short hsh[8 * 128];  // 2 KB: block's H1 tile (bf16)
    int g = threadIdx.x >> 5;                // group 0..7
    int d = blockIdx.x * 8 + g;
    int l = threadIdx.x & 31;
    int c0 = 4 * l;

    if (d < N) {
        const unsigned short* row = ell + (size_t)d * ELLW;
        int re = deg[d];

        float4 attv = *(const float4*)&att[c0];
        attv.x *= LOG2E; attv.y *= LOG2E; attv.z *= LOG2E; attv.w *= LOG2E;
        ushort4 xru = *(const ushort4*)&XR[(size_t)d * 128 + c0];
        float xr0 = bf2f(xru.x), xr1 = bf2f(xru.y), xr2 = bf2f(xru.z), xr3 = bf2f(xru.w);

        float ssum, a0, a1, a2, a3;
        float w_self, xs0, xs1, xs2, xs3;

#define LOADX1(s) (*(const ushort4*)&XL[(size_t)(s) * 128 + c0])
        // per-head (16-lane) reduce via DPP: quad xor1, xor2, then ror:4/ror:8
#define PROC1(xu)                                                          \
    {                                                                      \
        float x0 = bf2f(xu.x), x1 = bf2f(xu.y), x2 = bf2f(xu.z), x3 = bf2f(xu.w); \
        float p = leaky(x0 + xr0) * attv.x;                                \
        p = fmaf(leaky(x1 + xr1), attv.y, p);                              \
        p = fmaf(leaky(x2 + xr2), attv.z, p);                              \
        p = fmaf(leaky(x3 + xr3), attv.w, p);                              \
        p = dppadd<0xB1>(p);                                               \
        p = dppadd<0x4E>(p);                                               \
        p = dppadd<0x124>(p);                                              \
        p = dppadd<0x128>(p);                                              \
        float wgt = exp2f(p);                                              \
        ssum += wgt;                                                       \
        a0 = fmaf(wgt, x0, a0); a1 = fmaf(wgt, x1, a1);                    \
        a2 = fmaf(wgt, x2, a2); a3 = fmaf(wgt, x3, a3);                    \
    }

        {   // self loop; capture weight + features for pad-duplicate subtraction
            ushort4 xu = *(const ushort4*)&XL[(size_t)d * 128 + c0];
            xs0 = bf2f(xu.x); xs1 = bf2f(xu.y); xs2 = bf2f(xu.z); xs3 = bf2f(xu.w);
            float p = leaky(xs0 + xr0) * attv.x;
            p = fmaf(leaky(xs1 + xr1), attv.y, p);
            p = fmaf(leaky(xs2 + xr2), attv.z, p);
            p = fmaf(leaky(xs3 + xr3), attv.w, p);
            p = dppadd<0xB1>(p);
            p = dppadd<0x4E>(p);
            p = dppadd<0x124>(p);
            p = dppadd<0x128>(p);
            w_self = exp2f(p);
            ssum = w_self;
            a0 = w_self * xs0; a1 = w_self * xs1;
            a2 = w_self * xs2; a3 = w_self * xs3;
        }
        if (re > 0) {
            int rp = (re + 3) & ~3;   // pads (entries re..rp-1) are self rows
            ushort4 i0 = *(const ushort4*)&row[0];
            ushort4 b0 = LOADX1(i0.x), b1 = LOADX1(i0.y), b2 = LOADX1(i0.z), b3 = LOADX1(i0.w);
            for (int j = 0; j < rp; j += 4) {
                int j4 = j + 4 < ELLW - 3 ? j + 4 : ELLW - 4;
                ushort4 i1 = *(const ushort4*)&row[j4];
                ushort4 n0 = LOADX1(i1.x), n1 = LOADX1(i1.y), n2 = LOADX1(i1.z), n3 = LOADX1(i1.w);
                PROC1(b0);
                PROC1(b1);
                PROC1(b2);
                PROC1(b3);
                b0 = n0; b1 = n1; b2 = n2; b3 = n3;
            }
            // subtract the rp-re duplicate self contributions (weights identical)
            float kw = (float)(rp - re) * w_self;
            ssum -= kw;
            a0 = fmaf(-kw, xs0, a0); a1 = fmaf(-kw, xs1, a1);
            a2 = fmaf(-kw, xs2, a2); a3 = fmaf(-kw, xs3, a3);
        }
#undef PROC1
#undef LOADX1

        float inv = 1.0f / ssum;
        float4 bv = *(const float4*)&bias[c0];
        float r0 = fmaf(a0, inv, bv.x), r1 = fmaf(a1, inv, bv.y);
        float r2 = fmaf(a2, inv, bv.z), r3 = fmaf(a3, inv, bv.w);
        ushort4 o;
        o.x = (unsigned short)f2bf(r0 > 0.f ? r0 : 0.f);
        o.y = (unsigned short)f2bf(r1 > 0.f ? r1 : 0.f);
        o.z = (unsigned short)f2bf(r2 > 0.f ? r2 : 0.f);
        o.w = (unsigned short)f2bf(r3 > 0.f ? r3 : 0.f);
        *(ushort4*)&hsh[g * 128 + c0] = o;
    } else {
        // keep barrier validity; zero the tile row
        *(ushort4*)&hsh[g * 128 + c0] = make_ushort4(0, 0, 0, 0);
    }
    __syncthreads();

    // --- fused gemm2: [8 x 128] tile  x  Wcat2[64 x 128]^T -> XL2|XR2 ---
    // wave w handles channels [w*16, w*16+16); a-op = Wcat2 rows, b-op = H1 rows.
    {
        int w = threadIdx.x >> 6;          // 0..3
        int lane = threadIdx.x & 63;
        int ln = lane & 15;
        int quad = lane >> 4;
        f32x4 acc = (f32x4){0.f, 0.f, 0.f, 0.f};
#pragma unroll
        for (int kc = 0; kc < 4; ++kc) {
            int k0 = kc * 32 + quad * 8;
            bf16x8 a;
            if (ln < 8) a = *(const bf16x8*)&hsh[ln * 128 + k0];
            else        a = (bf16x8){0, 0, 0, 0, 0, 0, 0, 0};
            bf16x8 wv = *(const bf16x8*)(Wcat2 + (size_t)(w * 16 + ln) * 128 + k0);
            acc = __builtin_amdgcn_mfma_f32_16x16x32_bf16(wv, a, acc, 0, 0, 0);
        }
        int n = blockIdx.x * 8 + ln;       // node row (ln < 8 valid)
        if (ln < 8 && n < N) {
            int cb = w * 16 + quad * 4;
            float4 bv = *(const float4*)&bcat2[cb];
            ushort4 o;
            o.x = (unsigned short)f2bf(acc[0] + bv.x);
            o.y = (unsigned short)f2bf(acc[1] + bv.y);
            o.z = (unsigned short)f2bf(acc[2] + bv.z);
            o.w = (unsigned short)f2bf(acc[3] + bv.w);
            if (cb < 32) *(ushort4*)&XL2[(size_t)n * 32 + cb] = o;
            else         *(ushort4*)&XR2[(size_t)n * 32 + cb - 32] = o;
        }
    }
}

// ====== conv2: 8 lanes/node, implicit self-loop, pool replicas, uncond prefetch ======
__global__ __launch_bounds__(256) void node_conv2(const unsigned short* __restrict__ XL,
                                                  const unsigned short* __restrict__ XR,
                                                  const int* __restrict__ deg,
                                                  const unsigned short* __restrict__ ell,
                                                  const float* __restrict__ att,
                                                  const float* __restrict__ bias,
                                                  float* __restrict__ pooledR, int N) {
    __shared__ float psh[32];
    if (threadIdx.x < 32) psh[threadIdx.x] = 0.0f;
    __syncthreads();

    int slot = threadIdx.x >> 3;
    int l = threadIdx.x & 7;
    int c0 = 4 * l;
    float4 attv = *(const float4*)&att[c0];
    attv.x *= LOG2E; attv.y *= LOG2E; attv.z *= LOG2E; attv.w *= LOG2E;
    float4 bv = *(const float4*)&bias[c0];
    float p0 = 0.f, p1 = 0.f, p2 = 0.f, p3 = 0.f;

#define LOADX2(s) (*(const ushort4*)&XL[(size_t)(s) * 32 + c0])
    // 8-lane reduce via DPP: quad xor1, xor2, then row_half_mirror
#define PROC2(xu)                                                          \
    {                                                                      \
        float x0 = bf2f(xu.x), x1 = bf2f(xu.y), x2 = bf2f(xu.z), x3 = bf2f(xu.w); \
        float p = leaky(x0 + xr0) * attv.x;                                \
        p = fmaf(leaky(x1 + xr1), attv.y, p);                              \
        p = fmaf(leaky(x2 + xr2), attv.z, p);                              \
        p = fmaf(leaky(x3 + xr3), attv.w, p);                              \
        p = dppadd<0xB1>(p);                                               \
        p = dppadd<0x4E>(p);                                               \
        p = dppadd<0x141>(p);                                              \
        float wgt = exp2f(p);                                              \
        ssum += wgt;                                                       \
        a0 = fmaf(wgt, x0, a0); a1 = fmaf(wgt, x1, a1);                    \
        a2 = fmaf(wgt, x2, a2); a3 = fmaf(wgt, x3, a3);                    \
    }

    for (int d = blockIdx.x * 32 + slot; d < N; d += gridDim.x * 32) {
        const unsigned short* row = ell + (size_t)d * ELLW;
        int re = deg[d];
        ushort4 xru = *(const ushort4*)&XR[(size_t)d * 32 + c0];
        float xr0 = bf2f(xru.x), xr1 = bf2f(xru.y), xr2 = bf2f(xru.z), xr3 = bf2f(xru.w);
        float ssum, a0, a1, a2, a3;
        float w_self, xs0, xs1, xs2, xs3;

        {   // self loop; capture for pad-duplicate subtraction
            ushort4 xu = *(const ushort4*)&XL[(size_t)d * 32 + c0];
            xs0 = bf2f(xu.x); xs1 = bf2f(xu.y); xs2 = bf2f(xu.z); xs3 = bf2f(xu.w);
            float p = leaky(xs0 + xr0) * attv.x;
            p = fmaf(leaky(xs1 + xr1), attv.y, p);
            p = fmaf(leaky(xs2 + xr2), attv.z, p);
            p = fmaf(leaky(xs3 + xr3), attv.w, p);
            p = dppadd<0xB1>(p);
            p = dppadd<0x4E>(p);
            p = dppadd<0x141>(p);
            w_self = exp2f(p);
            ssum = w_self;
            a0 = w_self * xs0; a1 = w_self * xs1;
            a2 = w_self * xs2; a3 = w_self * xs3;
        }
        if (re > 0) {
            int rp = (re + 3) & ~3;
            ushort4 i0 = *(const ushort4*)&row[0];
            ushort4 b0 = LOADX2(i0.x), b1 = LOADX2(i0.y), b2 = LOADX2(i0.z), b3 = LOADX2(i0.w);
            for (int j = 0; j < rp; j += 4) {
                int j4 = j + 4 < ELLW - 3 ? j + 4 : ELLW - 4;
                ushort4 i1 = *(const ushort4*)&row[j4];
                ushort4 n0 = LOADX2(i1.x), n1 = LOADX2(i1.y), n2 = LOADX2(i1.z), n3 = LOADX2(i1.w);
                PROC2(b0);
                PROC2(b1);
                PROC2(b2);
                PROC2(b3);
                b0 = n0; b1 = n1; b2 = n2; b3 = n3;
            }
            float kw = (float)(rp - re) * w_self;
            ssum -= kw;
            a0 = fmaf(-kw, xs0, a0); a1 = fmaf(-kw, xs1, a1);
            a2 = fmaf(-kw, xs2, a2); a3 = fmaf(-kw, xs3, a3);
        }

        float inv = 1.0f / ssum;
        float r0 = fmaf(a0, inv, bv.x), r1 = fmaf(a1, inv, bv.y);
        float r2 = fmaf(a2, inv, bv.z), r3 = fmaf(a3, inv, bv.w);
        p0 += r0 > 0.f ? r0 : 0.f;
        p1 += r1 > 0.f ? r1 : 0.f;
        p2 += r2 > 0.f ? r2 : 0.f;
        p3 += r3 > 0.f ? r3 : 0.f;
    }
#undef PROC2
#undef LOADX2
    atomicAdd(&psh[c0 + 0], p0);
    atomicAdd(&psh[c0 + 1], p1);
    atomicAdd(&psh[c0 + 2], p2);
    atomicAdd(&psh[c0 + 3], p3);
    __syncthreads();
    float* rep = pooledR + (blockIdx.x & (NREP - 1)) * 32;
    if (threadIdx.x < 32) atomicAdd(&rep[threadIdx.x], psh[threadIdx.x]);
}

__global__ void out_kernel(const float* __restrict__ pooledR, const float* __restrict__ Wout,
                           const float* __restrict__ b_out, float* __restrict__ out, int N) {
    __shared__ float psum[32];
    if (threadIdx.x < 32) {
        float tot = 0.f;
#pragma unroll
        for (int r = 0; r < NREP; ++r) tot += pooledR[r * 32 + threadIdx.x];
        psum[threadIdx.x] = tot;
    }
    __syncthreads();
    int m = threadIdx.x;
    if (m < 96) {
        float invN = 1.0f / (float)N;
        float s = b_out[m];
#pragma unroll
        for (int c = 0; c < 32; ++c) s += (psum[c] * invN) * Wout[m * 32 + c];
        out[m] = s;
    }
}

extern "C" void kernel_launch(void* const* d_in, const int* in_sizes, int n_in,
                              void* d_out, int out_size, void* d_ws, size_t ws_size,
                              hipStream_t stream) {
    const float* x     = (const float*)d_in[0];
    const int*   ei    = (const int*)d_in[1];
    const float* Win   = (const float*)d_in[3];
    const float* b_in  = (const float*)d_in[4];
    const float* Wl1   = (const float*)d_in[5];
    const float* bl1   = (const float*)d_in[6];
    const float* Wr1   = (const float*)d_in[7];
    const float* br1   = (const float*)d_in[8];
    const float* att1  = (const float*)d_in[9];
    const float* bias1 = (const float*)d_in[10];
    const float* Wl2   = (const float*)d_in[11];
    const float* bl2   = (const float*)d_in[12];
    const float* Wr2   = (const float*)d_in[13];
    const float* br2   = (const float*)d_in[14];
    const float* att2  = (const float*)d_in[15];
    const float* bias2 = (const float*)d_in[16];
    const float* Wout  = (const float*)d_in[17];
    const float* b_out = (const float*)d_in[18];
    float* out = (float*)d_out;

    int N = in_sizes[0] / 128;  // 50000
    int E = in_sizes[1] / 2;    // 600000
    int NB = (N + 255) >> 8;    // 196 buckets

    char* wsb = (char*)d_ws;
    size_t off = 0;
    auto alloc = [&](size_t bytes) { void* p = wsb + off; off += (bytes + 255) & ~(size_t)255; return p; };

    unsigned short* XL1   = (unsigned short*)alloc((size_t)N * 128 * 2);
    unsigned short* XR1   = (unsigned short*)alloc((size_t)N * 128 * 2);
    unsigned short* XL2   = (unsigned short*)alloc((size_t)N * 32 * 2);
    unsigned short* XR2   = (unsigned short*)alloc((size_t)N * 32 * 2);
    unsigned short* Wcat1 = (unsigned short*)alloc(256 * 128 * 2);
    unsigned short* Wcat2 = (unsigned short*)alloc(64 * 128 * 2);
    float* bcat1   = (float*)alloc(256 * 4);
    float* bcat2   = (float*)alloc(64 * 4);
    float* pooledR = (float*)alloc(NREP * 32 * 4);
    int* bucketCnt = (int*)alloc(256 * 4);
    int* deg       = (int*)alloc((size_t)N * 4);
    unsigned int* region = (unsigned int*)alloc((size_t)NB * CAPB * 4);
    unsigned short* ell  = (unsigned short*)alloc((size_t)N * ELLW * 2);

    prep_kernel<<<163, 256, 0, stream>>>(Win, b_in, Wl1, bl1, Wr1, br1,
                                         Wl2, bl2, Wr2, br2,
                                         Wcat1, bcat1, Wcat2, bcat2, bucketCnt, pooledR, N);
    part_kernel<<<(E + CH - 1) / CH, 256, 0, stream>>>(ei, bucketCnt, region, E);
    ellb_kernel<<<NB, 256, 0, stream>>>(region, bucketCnt, ell, deg, N);
    gemm1_kernel<<<(N + 31) / 32, 256, 0, stream>>>(x, Wcat1, bcat1, XL1, XR1, N);
    node_conv1<<<(N + 7) / 8, 256, 0, stream>>>(XL1, XR1, deg, ell, att1, bias1,
                                                Wcat2, bcat2, XL2, XR2, N);
    node_conv2<<<1024, 256, 0, stream>>>(XL2, XR2, deg, ell, att2, bias2, pooledR, N);
    out_kernel<<<1, 128, 0, stream>>>(pooledR, Wout, b_out, out, N);
}

// Round 2
// 210.085 us; speedup vs baseline: 1.0689x; 1.0144x over previous
//
#include <hip/hip_runtime.h>
#include <hip/hip_bf16.h>
#include <math.h>

// GATv2 encoder, bucketed ushort-ELL (width 64, padded rows):
//   prep(fold+cat2+zero) -> fuse1(part ∥ gemm1-lo) -> fuse2(ellb ∥ gemm1-hi)
//   -> node_conv1(ring4 + FUSED gemm2 via LDS tile) -> node_conv2 -> out
// Lessons: grid.sync ~60us (R8); per-block __threadfence serializes (R10);
// kernel merging never overlaps *dependent* work, random global atomics
// saturate ~13 G/s (R13/R16); ELL pad kills prefetch clamps (R18);
// producer-block GEMM fusion removes the H1 round-trip (R19); DPP reduce
// kills ds_swizzle chains (R20).
// This round: heterogeneous-grid co-launch of independent kernels:
// gemm1 split in two halves, overlapped with part and ellb respectively
// (disjoint pipes: LDS-atomic/store vs MFMA/global-load). conv2 grid ->
// 1 node per slot (old grid gave 539 blocks a 2-node serial tail).

#define NEG_SLOPE 0.2f
#define LOG2E 1.4426950408889634f
#define NREP 16
#define ELLW 64
#define CH 2048
#define CAPB 8192

typedef __attribute__((ext_vector_type(8))) short bf16x8;
typedef __attribute__((ext_vector_type(4))) float f32x4;

__device__ __forceinline__ float leaky(float t) { return fmaxf(t, NEG_SLOPE * t); }
__device__ __forceinline__ float bf2f(unsigned short u) {
    return __uint_as_float((unsigned)u << 16);
}
__device__ __forceinline__ short f2bf(float f) {           // RNE
    __hip_bfloat16 h = __float2bfloat16(f);
    return *reinterpret_cast<short*>(&h);
}
__device__ __forceinline__ short f2bf_fast(float f) {      // round-half-up
    return (short)((__float_as_uint(f) + 0x8000u) >> 16);
}

// DPP cross-lane add: v += lane-permuted(v). CTRL: 0xB1 quad xor1,
// 0x4E quad xor2, 0x124 row_ror:4, 0x128 row_ror:8, 0x141 row_half_mirror.
template <int CTRL>
__device__ __forceinline__ float dppadd(float v) {
    int t = __builtin_amdgcn_update_dpp(0, __float_as_int(v), CTRL, 0xF, 0xF, true);
    return v + __int_as_float(t);
}

// ============ prep: fold1 (b<128) + cat2 (128<=b<160) + zero (b>=160) ============
__global__ __launch_bounds__(256) void prep_kernel(const float* __restrict__ Win,
                                                   const float* __restrict__ b_in,
                                                   const float* __restrict__ Wl1,
                                                   const float* __restrict__ bl1,
                                                   const float* __restrict__ Wr1,
                                                   const float* __restrict__ br1,
                                                   const float* __restrict__ Wl2,
                                                   const float* __restrict__ bl2,
                                                   const float* __restrict__ Wr2,
                                                   const float* __restrict__ br2,
                                                   unsigned short* __restrict__ Wcat1,
                                                   float* __restrict__ bcat1,
                                                   unsigned short* __restrict__ Wcat2,
                                                   float* __restrict__ bcat2,
                                                   int* __restrict__ bucketCnt,
                                                   float* __restrict__ pooledR, int N) {
    int b = blockIdx.x, t = threadIdx.x;
    if (b < 128) {
        int half = t >> 7;
        int k = t & 127;
        int o = b * 2 + half;
        const float* Wx = (o < 128) ? Wl1 : Wr1;
        const float* bx = (o < 128) ? bl1 : br1;
        int oo = o & 127;
        float acc = 0.f;
#pragma unroll 16
        for (int j = 0; j < 128; ++j)
            acc = fmaf(Wx[oo * 128 + j], Win[j * 128 + k], acc);
        Wcat1[o * 128 + k] = (unsigned short)f2bf(acc);

        __shared__ float red[256];
        red[t] = Wx[oo * 128 + k] * b_in[k];
        __syncthreads();
        for (int off = 64; off > 0; off >>= 1) {
            if (k < off) red[t] += red[t + off];
            __syncthreads();
        }
        if (k == 0) bcat1[o] = red[half * 128] + bx[oo];
    } else if (b < 160) {
        int i = (b - 128) * 256 + t;
        int m = i >> 7, kk = i & 127;
        float v = (m < 32) ? Wl2[m * 128 + kk] : Wr2[(m - 32) * 128 + kk];
        Wcat2[i] = (unsigned short)f2bf(v);
        if (b == 128 && t < 64) bcat2[t] = (t < 32) ? bl2[t] : br2[t - 32];
    } else if (b == 160) {
        if (t < 256) bucketCnt[t] = 0;
    } else {
        int i = (b - 161) * 256 + t;
        if (i < NREP * 32) pooledR[i] = 0.f;
    }
}

// ---------------- gemm1 body: f32 A, 32 rows x 256 ch, callable per-block ----------------
__device__ __forceinline__ void gemm1_body(const float* __restrict__ x,
                                           const unsigned short* __restrict__ W,
                                           const float* __restrict__ bias,
                                           unsigned short* __restrict__ XL,
                                           unsigned short* __restrict__ XR,
                                           int N, int nb) {
    const int w = threadIdx.x >> 6;
    const int lane = threadIdx.x & 63;
    const int ln = lane & 15;
    const int quad = lane >> 4;
    const int c0 = w * 64;

    int rows[2];
#pragma unroll
    for (int rt = 0; rt < 2; ++rt) {
        int n = nb + rt * 16 + ln;
        rows[rt] = n < N ? n : N - 1;
    }

    float4 araw[2][4][2];
#pragma unroll
    for (int rt = 0; rt < 2; ++rt)
#pragma unroll
        for (int kc = 0; kc < 4; ++kc) {
            const float* p = x + (size_t)rows[rt] * 128 + kc * 32 + quad * 8;
            araw[rt][kc][0] = *(const float4*)p;
            araw[rt][kc][1] = *(const float4*)(p + 4);
        }
    bf16x8 a[2][4];
#pragma unroll
    for (int rt = 0; rt < 2; ++rt)
#pragma unroll
        for (int kc = 0; kc < 4; ++kc) {
            float4 u = araw[rt][kc][0], v = araw[rt][kc][1];
            a[rt][kc][0] = f2bf_fast(u.x); a[rt][kc][1] = f2bf_fast(u.y);
            a[rt][kc][2] = f2bf_fast(u.z); a[rt][kc][3] = f2bf_fast(u.w);
            a[rt][kc][4] = f2bf_fast(v.x); a[rt][kc][5] = f2bf_fast(v.y);
            a[rt][kc][6] = f2bf_fast(v.z); a[rt][kc][7] = f2bf_fast(v.w);
        }

    f32x4 acc[2][4];
#pragma unroll
    for (int rt = 0; rt < 2; ++rt)
#pragma unroll
        for (int ct = 0; ct < 4; ++ct) acc[rt][ct] = (f32x4){0.f, 0.f, 0.f, 0.f};

#pragma unroll
    for (int kc = 0; kc < 4; ++kc) {
        const int k0 = kc * 32 + quad * 8;
        bf16x8 wv[4];
#pragma unroll
        for (int ct = 0; ct < 4; ++ct)
            wv[ct] = *(const bf16x8*)(W + (size_t)(c0 + ct * 16 + ln) * 128 + k0);
#pragma unroll
        for (int rt = 0; rt < 2; ++rt)
#pragma unroll
            for (int ct = 0; ct < 4; ++ct)
                acc[rt][ct] = __builtin_amdgcn_mfma_f32_16x16x32_bf16(wv[ct], a[rt][kc], acc[rt][ct], 0, 0, 0);
    }

#pragma unroll
    for (int rt = 0; rt < 2; ++rt) {
        int n = nb + rt * 16 + ln;
        if (n >= N) continue;
#pragma unroll
        for (int ct = 0; ct < 4; ++ct) {
            int cb = c0 + ct * 16 + quad * 4;
            float4 bv = *(const float4*)&bias[cb];
            ushort4 o;
            o.x = (unsigned short)f2bf(acc[rt][ct][0] + bv.x);
            o.y = (unsigned short)f2bf(acc[rt][ct][1] + bv.y);
            o.z = (unsigned short)f2bf(acc[rt][ct][2] + bv.z);
            o.w = (unsigned short)f2bf(acc[rt][ct][3] + bv.w);
            if (cb < 128) *(ushort4*)&XL[(size_t)n * 128 + cb] = o;
            else          *(ushort4*)&XR[(size_t)n * 128 + cb - 128] = o;
        }
    }
}

// ======== fuse1: part (blocks < PB) ∥ gemm1 nodes [0, GB1*32) ========
__global__ __launch_bounds__(256) void fuse1_kernel(const int* __restrict__ ei,
                                                    int* __restrict__ bucketCnt,
                                                    unsigned int* __restrict__ region,
                                                    int E,
                                                    const float* __restrict__ x,
                                                    const unsigned short* __restrict__ W,
                                                    const float* __restrict__ bias,
                                                    unsigned short* __restrict__ XL,
                                                    unsigned short* __restrict__ XR,
                                                    int N, int PB) {
    __shared__ int hist[256];
    __shared__ int base[256];
    __shared__ int off[256];
    if (blockIdx.x >= PB) {
        gemm1_body(x, W, bias, XL, XR, N, (blockIdx.x - PB) * 32);
        return;
    }
    int b = blockIdx.x, t = threadIdx.x;
    int e0 = b * CH;
    int e1 = e0 + CH; if (e1 > E) e1 = E;

    hist[t] = 0;
    __syncthreads();
    for (int e = e0 + t; e < e1; e += 256) {
        int d = ei[E + e];
        atomicAdd(&hist[d >> 8], 1);
    }
    __syncthreads();
    int h = hist[t];
    base[t] = (h > 0) ? atomicAdd(&bucketCnt[t], h) : 0;
    off[t] = 0;
    __syncthreads();
    for (int e = e0 + t; e < e1; e += 256) {
        int s = ei[e];
        int d = ei[E + e];
        int bk = d >> 8;
        int p = base[bk] + atomicAdd(&off[bk], 1);
        if (p < CAPB)
            region[(size_t)bk * CAPB + p] = (unsigned)s | ((unsigned)(d & 255) << 16);
    }
}

// ======== fuse2: ellb (blocks < NB) ∥ gemm1 nodes [nodeOff, N) ========
// NOTE: 33 KB static LDS applies to the gemm1 blocks too -> 4 blocks/CU for
// them (16 waves/CU); acceptable for the prefetch-deep MFMA body.
__global__ __launch_bounds__(256) void fuse2_kernel(const unsigned int* __restrict__ region,
                                                    const int* __restrict__ bucketCnt,
                                                    unsigned short* __restrict__ ell,
                                                    int* __restrict__ deg,
                                                    const float* __restrict__ x,
                                                    const unsigned short* __restrict__ W,
                                                    const float* __restrict__ bias,
                                                    unsigned short* __restrict__ XL,
                                                    unsigned short* __restrict__ XR,
                                                    int N, int NB, int nodeOff) {
    __shared__ unsigned short tile[256 * ELLW];  // 32 KB
    __shared__ int cur[256];
    if (blockIdx.x >= NB) {
        gemm1_body(x, W, bias, XL, XR, N, nodeOff + (blockIdx.x - NB) * 32);
        return;
    }
    int nb = blockIdx.x, t = threadIdx.x;
    cur[t] = 0;
    __syncthreads();
    int cnt = bucketCnt[nb];
    if (cnt > CAPB) cnt = CAPB;
    for (int i = t; i < cnt; i += 256) {
        unsigned p = region[(size_t)nb * CAPB + i];
        int doff = p >> 16;
        int s = p & 0xFFFF;
        int r = atomicAdd(&cur[doff], 1);
        if (r < ELLW) tile[doff * ELLW + r] = (unsigned short)s;
    }
    __syncthreads();
    int node = nb * 256 + t;
    int dgl = cur[t];
    if (dgl > ELLW) dgl = ELLW;
    if (node < N) {
        deg[node] = dgl;
        int pe = dgl + 8; if (pe > ELLW) pe = ELLW;
        for (int r = dgl; r < pe; ++r) tile[t * ELLW + r] = (unsigned short)node;
    }
    __syncthreads();
    const uint4* tl = (const uint4*)tile;
    uint4* gl = (uint4*)(ell + (size_t)nb * 256 * ELLW);
#pragma unroll
    for (int k = 0; k < 8; ++k) {
        int idx = t + k * 256;
        int row = idx >> 3;
        if (nb * 256 + row < N) gl[idx] = tl[idx];
    }
}

// ======= conv1 + fused gemm2: 8 nodes/block; ring4 gather then LDS-tile MFMA =======
__global__ __launch_bounds__(256) void node_conv1(const unsigned short* __restrict__ XL,
                                                  const unsigned short* __restrict__ XR,
                                                  const int* __restrict__ deg,
                                                  const unsigned short* __restrict__ ell,
                                                  const float* __restrict__ att,
                                                  const float* __restrict__ bias,
                                                  const unsigned short* __restrict__ Wcat2,
                                                  const float* __restrict__ bcat2,
                                                  unsigned short* __restrict__ XL2,
                                                  unsigned short* __restrict__ XR2, int N) {
    __shared__ unsigned short hsh[8 * 128];  // 2 KB: block's H1 tile (bf16)
    int g = threadIdx.x >> 5;                // group 0..7
    int d = blockIdx.x * 8 + g;
    int l = threadIdx.x & 31;
    int c0 = 4 * l;

    if (d < N) {
        const unsigned short* row = ell + (size_t)d * ELLW;
        int re = deg[d];

        float4 attv = *(const float4*)&att[c0];
        attv.x *= LOG2E; attv.y *= LOG2E; attv.z *= LOG2E; attv.w *= LOG2E;
        ushort4 xru = *(const ushort4*)&XR[(size_t)d * 128 + c0];
        float xr0 = bf2f(xru.x), xr1 = bf2f(xru.y), xr2 = bf2f(xru.z), xr3 = bf2f(xru.w);

        float ssum, a0, a1, a2, a3;
        float w_self, xs0, xs1, xs2, xs3;

#define LOADX1(s) (*(const ushort4*)&XL[(size_t)(s) * 128 + c0])
        // per-head (16-lane) reduce via DPP: quad xor1, xor2, then ror:4/ror:8
#define PROC1(xu)                                                          \
    {                                                                      \
        float x0 = bf2f(xu.x), x1 = bf2f(xu.y), x2 = bf2f(xu.z), x3 = bf2f(xu.w); \
        float p = leaky(x0 + xr0) * attv.x;                                \
        p = fmaf(leaky(x1 + xr1), attv.y, p);                              \
        p = fmaf(leaky(x2 + xr2), attv.z, p);                              \
        p = fmaf(leaky(x3 + xr3), attv.w, p);                              \
        p = dppadd<0xB1>(p);                                               \
        p = dppadd<0x4E>(p);                                               \
        p = dppadd<0x124>(p);                                              \
        p = dppadd<0x128>(p);                                              \
        float wgt = exp2f(p);                                              \
        ssum += wgt;                                                       \
        a0 = fmaf(wgt, x0, a0); a1 = fmaf(wgt, x1, a1);                    \
        a2 = fmaf(wgt, x2, a2); a3 = fmaf(wgt, x3, a3);                    \
    }

        {   // self loop; capture weight + features for pad-duplicate subtraction
            ushort4 xu = *(const ushort4*)&XL[(size_t)d * 128 + c0];
            xs0 = bf2f(xu.x); xs1 = bf2f(xu.y); xs2 = bf2f(xu.z); xs3 = bf2f(xu.w);
            float p = leaky(xs0 + xr0) * attv.x;
            p = fmaf(leaky(xs1 + xr1), attv.y, p);
            p = fmaf(leaky(xs2 + xr2), attv.z, p);
            p = fmaf(leaky(xs3 + xr3), attv.w, p);
            p = dppadd<0xB1>(p);
            p = dppadd<0x4E>(p);
            p = dppadd<0x124>(p);
            p = dppadd<0x128>(p);
            w_self = exp2f(p);
            ssum = w_self;
            a0 = w_self * xs0; a1 = w_self * xs1;
            a2 = w_self * xs2; a3 = w_self * xs3;
        }
        if (re > 0) {
            int rp = (re + 3) & ~3;   // pads (entries re..rp-1) are self rows
            ushort4 i0 = *(const ushort4*)&row[0];
            ushort4 b0 = LOADX1(i0.x), b1 = LOADX1(i0.y), b2 = LOADX1(i0.z), b3 = LOADX1(i0.w);
            for (int j = 0; j < rp; j += 4) {
                int j4 = j + 4 < ELLW - 3 ? j + 4 : ELLW - 4;
                ushort4 i1 = *(const ushort4*)&row[j4];
                ushort4 n0 = LOADX1(i1.x), n1 = LOADX1(i1.y), n2 = LOADX1(i1.z), n3 = LOADX1(i1.w);
                PROC1(b0);
                PROC1(b1);
                PROC1(b2);
                PROC1(b3);
                b0 = n0; b1 = n1; b2 = n2; b3 = n3;
            }
            // subtract the rp-re duplicate self contributions (weights identical)
            float kw = (float)(rp - re) * w_self;
            ssum -= kw;
            a0 = fmaf(-kw, xs0, a0); a1 = fmaf(-kw, xs1, a1);
            a2 = fmaf(-kw, xs2, a2); a3 = fmaf(-kw, xs3, a3);
        }
#undef PROC1
#undef LOADX1

        float inv = 1.0f / ssum;
        float4 bv = *(const float4*)&bias[c0];
        float r0 = fmaf(a0, inv, bv.x), r1 = fmaf(a1, inv, bv.y);
        float r2 = fmaf(a2, inv, bv.z), r3 = fmaf(a3, inv, bv.w);
        ushort4 o;
        o.x = (unsigned short)f2bf(r0 > 0.f ? r0 : 0.f);
        o.y = (unsigned short)f2bf(r1 > 0.f ? r1 : 0.f);
        o.z = (unsigned short)f2bf(r2 > 0.f ? r2 : 0.f);
        o.w = (unsigned short)f2bf(r3 > 0.f ? r3 : 0.f);
        *(ushort4*)&hsh[g * 128 + c0] = o;
    } else {
        // keep barrier validity; zero the tile row
        *(ushort4*)&hsh[g * 128 + c0] = make_ushort4(0, 0, 0, 0);
    }
    __syncthreads();

    // --- fused gemm2: [8 x 128] tile  x  Wcat2[64 x 128]^T -> XL2|XR2 ---
    // wave w handles channels [w*16, w*16+16); a-op = Wcat2 rows, b-op = H1 rows.
    {
        int w = threadIdx.x >> 6;          // 0..3
        int lane = threadIdx.x & 63;
        int ln = lane & 15;
        int quad = lane >> 4;
        f32x4 acc = (f32x4){0.f, 0.f, 0.f, 0.f};
#pragma unroll
        for (int kc = 0; kc < 4; ++kc) {
            int k0 = kc * 32 + quad * 8;
            bf16x8 a;
            if (ln < 8) a = *(const bf16x8*)&hsh[ln * 128 + k0];
            else        a = (bf16x8){0, 0, 0, 0, 0, 0, 0, 0};
            bf16x8 wv = *(const bf16x8*)(Wcat2 + (size_t)(w * 16 + ln) * 128 + k0);
            acc = __builtin_amdgcn_mfma_f32_16x16x32_bf16(wv, a, acc, 0, 0, 0);
        }
        int n = blockIdx.x * 8 + ln;       // node row (ln < 8 valid)
        if (ln < 8 && n < N) {
            int cb = w * 16 + quad * 4;
            float4 bv = *(const float4*)&bcat2[cb];
            ushort4 o;
            o.x = (unsigned short)f2bf(acc[0] + bv.x);
            o.y = (unsigned short)f2bf(acc[1] + bv.y);
            o.z = (unsigned short)f2bf(acc[2] + bv.z);
            o.w = (unsigned short)f2bf(acc[3] + bv.w);
            if (cb < 32) *(ushort4*)&XL2[(size_t)n * 32 + cb] = o;
            else         *(ushort4*)&XR2[(size_t)n * 32 + cb - 32] = o;
        }
    }
}

// ====== conv2: 8 lanes/node, implicit self-loop, pool replicas, uncond prefetch ======
__global__ __launch_bounds__(256) void node_conv2(const unsigned short* __restrict__ XL,
                                                  const unsigned short* __restrict__ XR,
                                                  const int* __restrict__ deg,
                                                  const unsigned short* __restrict__ ell,
                                                  const float* __restrict__ att,
                                                  const float* __restrict__ bias,
                                                  float* __restrict__ pooledR, int N) {
    __shared__ float psh[32];
    if (threadIdx.x < 32) psh[threadIdx.x] = 0.0f;
    __syncthreads();

    int slot = threadIdx.x >> 3;
    int l = threadIdx.x & 7;
    int c0 = 4 * l;
    float4 attv = *(const float4*)&att[c0];
    attv.x *= LOG2E; attv.y *= LOG2E; attv.z *= LOG2E; attv.w *= LOG2E;
    float4 bv = *(const float4*)&bias[c0];
    float p0 = 0.f, p1 = 0.f, p2 = 0.f, p3 = 0.f;

#define LOADX2(s) (*(const ushort4*)&XL[(size_t)(s) * 32 + c0])
    // 8-lane reduce via DPP: quad xor1, xor2, then row_half_mirror
#define PROC2(xu)                                                          \
    {                                                                      \
        float x0 = bf2f(xu.x), x1 = bf2f(xu.y), x2 = bf2f(xu.z), x3 = bf2f(xu.w); \
        float p = leaky(x0 + xr0) * attv.x;                                \
        p = fmaf(leaky(x1 + xr1), attv.y, p);                              \
        p = fmaf(leaky(x2 + xr2), attv.z, p);                              \
        p = fmaf(leaky(x3 + xr3), attv.w, p);                              \
        p = dppadd<0xB1>(p);                                               \
        p = dppadd<0x4E>(p);                                               \
        p = dppadd<0x141>(p);                                              \
        float wgt = exp2f(p);                                              \
        ssum += wgt;                                                       \
        a0 = fmaf(wgt, x0, a0); a1 = fmaf(wgt, x1, a1);                    \
        a2 = fmaf(wgt, x2, a2); a3 = fmaf(wgt, x3, a3);                    \
    }

    for (int d = blockIdx.x * 32 + slot; d < N; d += gridDim.x * 32) {
        const unsigned short* row = ell + (size_t)d * ELLW;
        int re = deg[d];
        ushort4 xru = *(const ushort4*)&XR[(size_t)d * 32 + c0];
        float xr0 = bf2f(xru.x), xr1 = bf2f(xru.y), xr2 = bf2f(xru.z), xr3 = bf2f(xru.w);
        float ssum, a0, a1, a2, a3;
        float w_self, xs0, xs1, xs2, xs3;

        {   // self loop; capture for pad-duplicate subtraction
            ushort4 xu = *(const ushort4*)&XL[(size_t)d * 32 + c0];
            xs0 = bf2f(xu.x); xs1 = bf2f(xu.y); xs2 = bf2f(xu.z); xs3 = bf2f(xu.w);
            float p = leaky(xs0 + xr0) * attv.x;
            p = fmaf(leaky(xs1 + xr1), attv.y, p);
            p = fmaf(leaky(xs2 + xr2), attv.z, p);
            p = fmaf(leaky(xs3 + xr3), attv.w, p);
            p = dppadd<0xB1>(p);
            p = dppadd<0x4E>(p);
            p = dppadd<0x141>(p);
            w_self = exp2f(p);
            ssum = w_self;
            a0 = w_self * xs0; a1 = w_self * xs1;
            a2 = w_self * xs2; a3 = w_self * xs3;
        }
        if (re > 0) {
            int rp = (re + 3) & ~3;
            ushort4 i0 = *(const ushort4*)&row[0];
            ushort4 b0 = LOADX2(i0.x), b1 = LOADX2(i0.y), b2 = LOADX2(i0.z), b3 = LOADX2(i0.w);
            for (int j = 0; j < rp; j += 4) {
                int j4 = j + 4 < ELLW - 3 ? j + 4 : ELLW - 4;
                ushort4 i1 = *(const ushort4*)&row[j4];
                ushort4 n0 = LOADX2(i1.x), n1 = LOADX2(i1.y), n2 = LOADX2(i1.z), n3 = LOADX2(i1.w);
                PROC2(b0);
                PROC2(b1);
                PROC2(b2);
                PROC2(b3);
                b0 = n0; b1 = n1; b2 = n2; b3 = n3;
            }
            float kw = (float)(rp - re) * w_self;
            ssum -= kw;
            a0 = fmaf(-kw, xs0, a0); a1 = fmaf(-kw, xs1, a1);
            a2 = fmaf(-kw, xs2, a2); a3 = fmaf(-kw, xs3, a3);
        }

        float inv = 1.0f / ssum;
        float r0 = fmaf(a0, inv, bv.x), r1 = fmaf(a1, inv, bv.y);
        float r2 = fmaf(a2, inv, bv.z), r3 = fmaf(a3, inv, bv.w);
        p0 += r0 > 0.f ? r0 : 0.f;
        p1 += r1 > 0.f ? r1 : 0.f;
        p2 += r2 > 0.f ? r2 : 0.f;
        p3 += r3 > 0.f ? r3 : 0.f;
    }
#undef PROC2
#undef LOADX2
    atomicAdd(&psh[c0 + 0], p0);
    atomicAdd(&psh[c0 + 1], p1);
    atomicAdd(&psh[c0 + 2], p2);
    atomicAdd(&psh[c0 + 3], p3);
    __syncthreads();
    float* rep = pooledR + (blockIdx.x & (NREP - 1)) * 32;
    if (threadIdx.x < 32) atomicAdd(&rep[threadIdx.x], psh[threadIdx.x]);
}

__global__ void out_kernel(const float* __restrict__ pooledR, const float* __restrict__ Wout,
                           const float* __restrict__ b_out, float* __restrict__ out, int N) {
    __shared__ float psum[32];
    if (threadIdx.x < 32) {
        float tot = 0.f;
#pragma unroll
        for (int r = 0; r < NREP; ++r) tot += pooledR[r * 32 + threadIdx.x];
        psum[threadIdx.x] = tot;
    }
    __syncthreads();
    int m = threadIdx.x;
    if (m < 96) {
        float invN = 1.0f / (float)N;
        float s = b_out[m];
#pragma unroll
        for (int c = 0; c < 32; ++c) s += (psum[c] * invN) * Wout[m * 32 + c];
        out[m] = s;
    }
}

extern "C" void kernel_launch(void* const* d_in, const int* in_sizes, int n_in,
                              void* d_out, int out_size, void* d_ws, size_t ws_size,
                              hipStream_t stream) {
    const float* x     = (const float*)d_in[0];
    const int*   ei    = (const int*)d_in[1];
    const float* Win   = (const float*)d_in[3];
    const float* b_in  = (const float*)d_in[4];
    const float* Wl1   = (const float*)d_in[5];
    const float* bl1   = (const float*)d_in[6];
    const float* Wr1   = (const float*)d_in[7];
    const float* br1   = (const float*)d_in[8];
    const float* att1  = (const float*)d_in[9];
    const float* bias1 = (const float*)d_in[10];
    const float* Wl2   = (const float*)d_in[11];
    const float* bl2   = (const float*)d_in[12];
    const float* Wr2   = (const float*)d_in[13];
    const float* br2   = (const float*)d_in[14];
    const float* att2  = (const float*)d_in[15];
    const float* bias2 = (const float*)d_in[16];
    const float* Wout  = (const float*)d_in[17];
    const float* b_out = (const float*)d_in[18];
    float* out = (float*)d_out;

    int N = in_sizes[0] / 128;  // 50000
    int E = in_sizes[1] / 2;    // 600000
    int NB = (N + 255) >> 8;    // 196 buckets

    char* wsb = (char*)d_ws;
    size_t off = 0;
    auto alloc = [&](size_t bytes) { void* p = wsb + off; off += (bytes + 255) & ~(size_t)255; return p; };

    unsigned short* XL1   = (unsigned short*)alloc((size_t)N * 128 * 2);
    unsigned short* XR1   = (unsigned short*)alloc((size_t)N * 128 * 2);
    unsigned short* XL2   = (unsigned short*)alloc((size_t)N * 32 * 2);
    unsigned short* XR2   = (unsigned short*)alloc((size_t)N * 32 * 2);
    unsigned short* Wcat1 = (unsigned short*)alloc(256 * 128 * 2);
    unsigned short* Wcat2 = (unsigned short*)alloc(64 * 128 * 2);
    float* bcat1   = (float*)alloc(256 * 4);
    float* bcat2   = (float*)alloc(64 * 4);
    float* pooledR = (float*)alloc(NREP * 32 * 4);
    int* bucketCnt = (int*)alloc(256 * 4);
    int* deg       = (int*)alloc((size_t)N * 4);
    unsigned int* region = (unsigned int*)alloc((size_t)NB * CAPB * 4);
    unsigned short* ell  = (unsigned short*)alloc((size_t)N * ELLW * 2);

    int PB  = (E + CH - 1) / CH;        // 293 partition blocks
    int GT  = (N + 31) / 32;            // 1563 gemm1 blocks total
    int GB1 = GT / 2;                   // overlap with part
    int GB2 = GT - GB1;                 // overlap with ellb

    prep_kernel<<<163, 256, 0, stream>>>(Win, b_in, Wl1, bl1, Wr1, br1,
                                         Wl2, bl2, Wr2, br2,
                                         Wcat1, bcat1, Wcat2, bcat2, bucketCnt, pooledR, N);
    fuse1_kernel<<<PB + GB1, 256, 0, stream>>>(ei, bucketCnt, region, E,
                                               x, Wcat1, bcat1, XL1, XR1, N, PB);
    fuse2_kernel<<<NB + GB2, 256, 0, stream>>>(region, bucketCnt, ell, deg,
                                               x, Wcat1, bcat1, XL1, XR1, N, NB, GB1 * 32);
    node_conv1<<<(N + 7) / 8, 256, 0, stream>>>(XL1, XR1, deg, ell, att1, bias1,
                                                Wcat2, bcat2, XL2, XR2, N);
    node_conv2<<<GT, 256, 0, stream>>>(XL2, XR2, deg, ell, att2, bias2, pooledR, N);
    out_kernel<<<1, 128, 0, stream>>>(pooledR, Wout, b_out, out, N);
}